// Round 1
// baseline (400.320 us; speedup 1.0000x reference)
//
#include <hip/hip_runtime.h>
#include <hip/hip_bf16.h>

typedef unsigned short u16;
typedef unsigned int u32;

#define HDIM 64
#define EPS 1e-5f

// ---------- helpers ----------

__device__ __forceinline__ float wave_sum64(float v) {
    v += __shfl_xor(v, 1, 64);
    v += __shfl_xor(v, 2, 64);
    v += __shfl_xor(v, 4, 64);
    v += __shfl_xor(v, 8, 64);
    v += __shfl_xor(v, 16, 64);
    v += __shfl_xor(v, 32, 64);
    return v;
}

// layernorm of one 64-elem row held one element per lane
__device__ __forceinline__ float lnorm(float v, float g, float b) {
    float mu = wave_sum64(v) * 0.015625f;        // /64
    float d  = v - mu;
    float var = wave_sum64(d * d) * 0.015625f;
    return d * rsqrtf(var + EPS) * g + b;
}

__device__ __forceinline__ float bcast(float v, int k) {
    return __int_as_float(__builtin_amdgcn_readlane(__float_as_int(v), k));
}

// round-to-nearest-even f32 -> bf16 bits
__device__ __forceinline__ u16 f2bf(float f) {
    u32 u = __float_as_uint(f);
    u32 r = (u + 0x7fffu + ((u >> 16) & 1u)) >> 16;
    return (u16)r;
}

// ---------- phase 1: per-node transform -> bf16 tables ----------
// T1[n] = LN(relu(LN(zz[n])@W1^T+b1)) @ bil_w      (row vector, H)
// T2[n] = LN(relu(LN(zz[n])@W2^T+b2))              (row vector, H)
__global__ __launch_bounds__(256) void phase1_kernel(
    const float* __restrict__ z,
    const float* __restrict__ root_w, const float* __restrict__ root_b,
    const float* __restrict__ lin1_w, const float* __restrict__ lin1_b,
    const float* __restrict__ lin2_w, const float* __restrict__ lin2_b,
    const float* __restrict__ bil_w,
    const float* __restrict__ norm_g, const float* __restrict__ norm_b,
    u16* __restrict__ T1, u16* __restrict__ T2, int nnodes)
{
    // transposed so reads W1t[k*64+lane] are lane-consecutive (conflict-free)
    __shared__ float W1t[4096], W2t[4096], Bs[4096];
    const int tid = threadIdx.x;
    for (int i = tid; i < 4096; i += 256) {
        int h = i >> 6, k = i & 63;
        W1t[(k << 6) | h] = lin1_w[i];
        W2t[(k << 6) | h] = lin2_w[i];
        Bs[i] = bil_w[i];       // accessed as Bs[h*64+lane]: already row-major
    }
    __syncthreads();

    const int lane = tid & 63;
    const float g  = norm_g[lane], bt = norm_b[lane];
    const float b1 = lin1_b[lane], b2 = lin2_b[lane];

    const int gwave = (blockIdx.x * 256 + tid) >> 6;
    const int n0 = gwave * 4;            // 4 nodes per wave
    if (n0 >= nnodes) return;

    float ln[4];
#pragma unroll
    for (int j = 0; j < 4; ++j) {
        int n = n0 + j;
        float v;
        if (n == 0)           v = root_w[lane] + root_b[lane];
        else if (n < nnodes)  v = z[(size_t)(n - 1) * HDIM + lane];
        else                  v = 0.f;
        ln[j] = lnorm(v, g, bt);
    }

    float a1[4] = {0.f,0.f,0.f,0.f}, a2[4] = {0.f,0.f,0.f,0.f};
#pragma unroll
    for (int k = 0; k < 64; ++k) {
        float w1k = W1t[(k << 6) | lane];
        float w2k = W2t[(k << 6) | lane];
#pragma unroll
        for (int j = 0; j < 4; ++j) {
            float s = bcast(ln[j], k);
            a1[j] = fmaf(s, w1k, a1[j]);
            a2[j] = fmaf(s, w2k, a2[j]);
        }
    }

    float x1[4], x2[4];
#pragma unroll
    for (int j = 0; j < 4; ++j) {
        x1[j] = lnorm(fmaxf(a1[j] + b1, 0.f), g, bt);
        x2[j] = lnorm(fmaxf(a2[j] + b2, 0.f), g, bt);
    }

    float w1[4] = {0.f,0.f,0.f,0.f};
#pragma unroll
    for (int h = 0; h < 64; ++h) {
        float bh = Bs[(h << 6) | lane];
#pragma unroll
        for (int j = 0; j < 4; ++j) {
            float s = bcast(x1[j], h);
            w1[j] = fmaf(s, bh, w1[j]);
        }
    }

#pragma unroll
    for (int j = 0; j < 4; ++j) {
        int n = n0 + j;
        if (n < nnodes) {
            T1[(size_t)n * HDIM + lane] = f2bf(w1[j]);
            T2[(size_t)n * HDIM + lane] = f2bf(x2[j]);
        }
    }
}

// ---------- phase 2: per-edge gather + 64-dot ----------
// 8 lanes per edge; each lane loads 8 bf16 (16B) from each table row.
__global__ __launch_bounds__(256) void phase2_kernel(
    const int* __restrict__ arcs,       // (E,2) int32
    const u16* __restrict__ T1, const u16* __restrict__ T2,
    const float* __restrict__ bil_b,
    float* __restrict__ out, int E)
{
    const int tid = blockIdx.x * 256 + threadIdx.x;
    const int e = tid >> 3;
    if (e >= E) return;
    const int l8 = tid & 7;

    const int i0 = arcs[2 * e];
    const int i1 = arcs[2 * e + 1];

    const uint4* p1 = (const uint4*)(T1 + (size_t)i0 * HDIM) + l8;
    const uint4* p2 = (const uint4*)(T2 + (size_t)i1 * HDIM) + l8;
    uint4 u = *p1;
    uint4 v = *p2;

    float s = 0.f;
    {
        u32 ua[4] = {u.x, u.y, u.z, u.w};
        u32 va[4] = {v.x, v.y, v.z, v.w};
#pragma unroll
        for (int i = 0; i < 4; ++i) {
            float alo = __uint_as_float(ua[i] << 16);
            float ahi = __uint_as_float(ua[i] & 0xffff0000u);
            float blo = __uint_as_float(va[i] << 16);
            float bhi = __uint_as_float(va[i] & 0xffff0000u);
            s = fmaf(alo, blo, s);
            s = fmaf(ahi, bhi, s);
        }
    }
    // reduce across the 8 lanes of this edge (masks <8 stay in-group)
    s += __shfl_xor(s, 1, 64);
    s += __shfl_xor(s, 2, 64);
    s += __shfl_xor(s, 4, 64);
    if (l8 == 0) out[e] = s + bil_b[0];
}

// ---------- fallback: per-edge full recompute (if ws too small) ----------
__global__ __launch_bounds__(256) void edge_direct_kernel(
    const float* __restrict__ z, const int* __restrict__ arcs,
    const float* __restrict__ root_w, const float* __restrict__ root_b,
    const float* __restrict__ lin1_w, const float* __restrict__ lin1_b,
    const float* __restrict__ lin2_w, const float* __restrict__ lin2_b,
    const float* __restrict__ bil_w, const float* __restrict__ bil_b,
    const float* __restrict__ norm_g, const float* __restrict__ norm_b,
    float* __restrict__ out, int E, int nnodes)
{
    __shared__ float W1t[4096], W2t[4096], Bs[4096];
    const int tid = threadIdx.x;
    for (int i = tid; i < 4096; i += 256) {
        int h = i >> 6, k = i & 63;
        W1t[(k << 6) | h] = lin1_w[i];
        W2t[(k << 6) | h] = lin2_w[i];
        Bs[i] = bil_w[i];
    }
    __syncthreads();

    const int lane = tid & 63;
    const float g  = norm_g[lane], bt = norm_b[lane];
    const float b1 = lin1_b[lane], b2 = lin2_b[lane];
    const float rootv = root_w[lane] + root_b[lane];

    const int gwave = (blockIdx.x * 256 + tid) >> 6;
    const int nwaves = (gridDim.x * 256) >> 6;

    for (int e = gwave; e < E; e += nwaves) {
        int i0 = arcs[2 * e], i1 = arcs[2 * e + 1];
        float v0 = (i0 == 0) ? rootv : z[(size_t)(i0 - 1) * HDIM + lane];
        float v1 = (i1 == 0) ? rootv : z[(size_t)(i1 - 1) * HDIM + lane];
        float l0 = lnorm(v0, g, bt);
        float l1 = lnorm(v1, g, bt);
        float a1 = 0.f, a2 = 0.f;
#pragma unroll
        for (int k = 0; k < 64; ++k) {
            a1 = fmaf(bcast(l0, k), W1t[(k << 6) | lane], a1);
            a2 = fmaf(bcast(l1, k), W2t[(k << 6) | lane], a2);
        }
        float x1 = lnorm(fmaxf(a1 + b1, 0.f), g, bt);
        float x2 = lnorm(fmaxf(a2 + b2, 0.f), g, bt);
        float w1 = 0.f;
#pragma unroll
        for (int h = 0; h < 64; ++h)
            w1 = fmaf(bcast(x1, h), Bs[(h << 6) | lane], w1);
        float sc = wave_sum64(w1 * x2);
        if (lane == 0) out[e] = sc + bil_b[0];
    }
}

// ---------- launch ----------
extern "C" void kernel_launch(void* const* d_in, const int* in_sizes, int n_in,
                              void* d_out, int out_size, void* d_ws, size_t ws_size,
                              hipStream_t stream) {
    const float* z      = (const float*)d_in[0];
    const int*   arcs   = (const int*)  d_in[1];
    const float* root_w = (const float*)d_in[2];
    const float* root_b = (const float*)d_in[3];
    const float* lin1_w = (const float*)d_in[4];
    const float* lin1_b = (const float*)d_in[5];
    const float* lin2_w = (const float*)d_in[6];
    const float* lin2_b = (const float*)d_in[7];
    const float* bil_w  = (const float*)d_in[8];
    const float* bil_b  = (const float*)d_in[9];
    const float* norm_g = (const float*)d_in[10];
    const float* norm_b = (const float*)d_in[11];
    float* out = (float*)d_out;

    const int E      = in_sizes[1] / 2;
    const int nnodes = in_sizes[0] / HDIM + 1;   // +1 for root row

    const size_t tbl  = (size_t)nnodes * HDIM * sizeof(u16);
    const size_t need = 2 * tbl;

    if (ws_size >= need) {
        u16* T1 = (u16*)d_ws;
        u16* T2 = (u16*)((char*)d_ws + tbl);

        const int waves1  = (nnodes + 3) / 4;
        const int blocks1 = (waves1 + 3) / 4;      // 4 waves per block
        phase1_kernel<<<blocks1, 256, 0, stream>>>(
            z, root_w, root_b, lin1_w, lin1_b, lin2_w, lin2_b,
            bil_w, norm_g, norm_b, T1, T2, nnodes);

        const long long thr2 = (long long)E * 8;
        const int blocks2 = (int)((thr2 + 255) / 256);
        phase2_kernel<<<blocks2, 256, 0, stream>>>(arcs, T1, T2, bil_b, out, E);
    } else {
        edge_direct_kernel<<<8192, 256, 0, stream>>>(
            z, arcs, root_w, root_b, lin1_w, lin1_b, lin2_w, lin2_b,
            bil_w, bil_b, norm_g, norm_b, out, E, nnodes);
    }
}

// Round 3
// 234.500 us; speedup vs baseline: 1.7071x; 1.7071x over previous
//
#include <hip/hip_runtime.h>
#include <hip/hip_bf16.h>

typedef unsigned short u16;
typedef unsigned int u32;

#define HDIM 64
#define EPS 1e-5f

// ---------- helpers ----------

__device__ __forceinline__ float wave_sum64(float v) {
    v += __shfl_xor(v, 1, 64);
    v += __shfl_xor(v, 2, 64);
    v += __shfl_xor(v, 4, 64);
    v += __shfl_xor(v, 8, 64);
    v += __shfl_xor(v, 16, 64);
    v += __shfl_xor(v, 32, 64);
    return v;
}

__device__ __forceinline__ float bcast(float v, int k) {
    return __int_as_float(__builtin_amdgcn_readlane(__float_as_int(v), k));
}

// round-to-nearest-even f32 -> bf16 bits
__device__ __forceinline__ u16 f2bf(float f) {
    u32 u = __float_as_uint(f);
    u32 r = (u + 0x7fffu + ((u >> 16) & 1u)) >> 16;
    return (u16)r;
}

// lane-local layernorm of a 64-float register array.
// 4-way partial sums keep the dependency chains short (16 deep, ILP 4).
#define LANE_LN(arr, gptr, bptr) do {                                   \
    float s0_ = 0.f, s1_ = 0.f, s2_ = 0.f, s3_ = 0.f;                   \
    _Pragma("unroll")                                                   \
    for (int k_ = 0; k_ < 64; k_ += 4) {                                \
        s0_ += (arr)[k_]; s1_ += (arr)[k_+1];                           \
        s2_ += (arr)[k_+2]; s3_ += (arr)[k_+3];                         \
    }                                                                   \
    const float mu_ = (s0_ + s1_ + s2_ + s3_) * 0.015625f;              \
    float v0_ = 0.f, v1_ = 0.f, v2_ = 0.f, v3_ = 0.f;                   \
    _Pragma("unroll")                                                   \
    for (int k_ = 0; k_ < 64; k_ += 4) {                                \
        float d0_ = (arr)[k_]   - mu_;  v0_ = fmaf(d0_, d0_, v0_);      \
        float d1_ = (arr)[k_+1] - mu_;  v1_ = fmaf(d1_, d1_, v1_);      \
        float d2_ = (arr)[k_+2] - mu_;  v2_ = fmaf(d2_, d2_, v2_);      \
        float d3_ = (arr)[k_+3] - mu_;  v3_ = fmaf(d3_, d3_, v3_);      \
    }                                                                   \
    const float rs_ = rsqrtf((v0_+v1_+v2_+v3_) * 0.015625f + EPS);      \
    _Pragma("unroll")                                                   \
    for (int k_ = 0; k_ < 64; ++k_)                                     \
        (arr)[k_] = ((arr)[k_] - mu_) * rs_ * (gptr)[k_] + (bptr)[k_];  \
} while (0)

// ---------- phase 1: per-node transform -> bf16 tables ----------
// Node-per-lane: each lane holds one node's 64-float row in registers.
// LN is lane-local (no shuffles); weights read from LDS at wave-uniform
// addresses (broadcast, conflict-free), 1 ds_read_b128 per 8 FMAs.
__global__ __launch_bounds__(256, 2) void phase1_kernel(
    const float* __restrict__ z,
    const float* __restrict__ root_w, const float* __restrict__ root_b,
    const float* __restrict__ lin1_w, const float* __restrict__ lin1_b,
    const float* __restrict__ lin2_w, const float* __restrict__ lin2_b,
    const float* __restrict__ bil_w,
    const float* __restrict__ norm_g, const float* __restrict__ norm_b,
    u16* __restrict__ T1, u16* __restrict__ T2, int nnodes)
{
    // W1t[k*64+h] = lin1_w[h*64+k]  (transpose done on the global-read side
    // so LDS writes are linear & conflict-free; compute reads are uniform).
    __shared__ float W1t[4096], W2t[4096], Bs[4096];
    __shared__ float gbuf[64], bbuf[64], b1buf[64], b2buf[64];

    const int tid = threadIdx.x;
    for (int i = tid; i < 4096; i += 256) {
        const int k = i >> 6, h = i & 63;
        W1t[i] = lin1_w[(h << 6) | k];
        W2t[i] = lin2_w[(h << 6) | k];
        Bs[i]  = bil_w[i];               // Bs[h*64+g], row-major as given
    }
    if (tid < 64) {
        gbuf[tid]  = norm_g[tid];
        bbuf[tid]  = norm_b[tid];
        b1buf[tid] = lin1_b[tid];
        b2buf[tid] = lin2_b[tid];
    }
    __syncthreads();

    const int node = blockIdx.x * 256 + tid;
    if (node >= nnodes) return;

    // ---- load row, LN ----
    float r[64];
    if (node == 0) {
#pragma unroll
        for (int k = 0; k < 64; ++k) r[k] = root_w[k] + root_b[k];
    } else {
        const float4* zp = (const float4*)(z + (size_t)(node - 1) * HDIM);
#pragma unroll
        for (int q = 0; q < 16; ++q) {
            float4 v = zp[q];
            r[4*q] = v.x; r[4*q+1] = v.y; r[4*q+2] = v.z; r[4*q+3] = v.w;
        }
    }
    LANE_LN(r, gbuf, bbuf);

    // ---- both 64x64 matmuls (bias-init accumulators) ----
    float a1[64], a2[64];
#pragma unroll
    for (int h = 0; h < 64; ++h) { a1[h] = b1buf[h]; a2[h] = b2buf[h]; }
#pragma unroll
    for (int k = 0; k < 64; ++k) {
        const float s = r[k];
        const float4* w1 = (const float4*)&W1t[k << 6];
        const float4* w2 = (const float4*)&W2t[k << 6];
#pragma unroll
        for (int q = 0; q < 16; ++q) {
            float4 u = w1[q];
            a1[4*q]   = fmaf(s, u.x, a1[4*q]);
            a1[4*q+1] = fmaf(s, u.y, a1[4*q+1]);
            a1[4*q+2] = fmaf(s, u.z, a1[4*q+2]);
            a1[4*q+3] = fmaf(s, u.w, a1[4*q+3]);
            float4 v = w2[q];
            a2[4*q]   = fmaf(s, v.x, a2[4*q]);
            a2[4*q+1] = fmaf(s, v.y, a2[4*q+1]);
            a2[4*q+2] = fmaf(s, v.z, a2[4*q+2]);
            a2[4*q+3] = fmaf(s, v.w, a2[4*q+3]);
        }
    }

    // ---- relu + LN ----
#pragma unroll
    for (int h = 0; h < 64; ++h) {
        a1[h] = fmaxf(a1[h], 0.f);
        a2[h] = fmaxf(a2[h], 0.f);
    }
    LANE_LN(a1, gbuf, bbuf);
    LANE_LN(a2, gbuf, bbuf);

    // ---- t = x1 @ bil_w ----
    float t[64];
#pragma unroll
    for (int g = 0; g < 64; ++g) t[g] = 0.f;
#pragma unroll
    for (int h = 0; h < 64; ++h) {
        const float s = a1[h];
        const float4* bw = (const float4*)&Bs[h << 6];
#pragma unroll
        for (int q = 0; q < 16; ++q) {
            float4 u = bw[q];
            t[4*q]   = fmaf(s, u.x, t[4*q]);
            t[4*q+1] = fmaf(s, u.y, t[4*q+1]);
            t[4*q+2] = fmaf(s, u.z, t[4*q+2]);
            t[4*q+3] = fmaf(s, u.w, t[4*q+3]);
        }
    }

    // ---- pack bf16 + store (per-lane contiguous 128B rows) ----
    uint4* o1 = (uint4*)(T1 + (size_t)node * HDIM);
    uint4* o2 = (uint4*)(T2 + (size_t)node * HDIM);
#pragma unroll
    for (int q = 0; q < 8; ++q) {
        uint4 w;
        w.x = (u32)f2bf(t[8*q])   | ((u32)f2bf(t[8*q+1]) << 16);
        w.y = (u32)f2bf(t[8*q+2]) | ((u32)f2bf(t[8*q+3]) << 16);
        w.z = (u32)f2bf(t[8*q+4]) | ((u32)f2bf(t[8*q+5]) << 16);
        w.w = (u32)f2bf(t[8*q+6]) | ((u32)f2bf(t[8*q+7]) << 16);
        o1[q] = w;
        uint4 x;
        x.x = (u32)f2bf(a2[8*q])   | ((u32)f2bf(a2[8*q+1]) << 16);
        x.y = (u32)f2bf(a2[8*q+2]) | ((u32)f2bf(a2[8*q+3]) << 16);
        x.z = (u32)f2bf(a2[8*q+4]) | ((u32)f2bf(a2[8*q+5]) << 16);
        x.w = (u32)f2bf(a2[8*q+6]) | ((u32)f2bf(a2[8*q+7]) << 16);
        o2[q] = x;
    }
}

// ---------- phase 2: per-edge gather + 64-dot ----------
__global__ __launch_bounds__(256) void phase2_kernel(
    const int* __restrict__ arcs,
    const u16* __restrict__ T1, const u16* __restrict__ T2,
    const float* __restrict__ bil_b,
    float* __restrict__ out, int E)
{
    const int tid = blockIdx.x * 256 + threadIdx.x;
    const int e = tid >> 3;
    if (e >= E) return;
    const int l8 = tid & 7;

    const int i0 = arcs[2 * e];
    const int i1 = arcs[2 * e + 1];

    const uint4* p1 = (const uint4*)(T1 + (size_t)i0 * HDIM) + l8;
    const uint4* p2 = (const uint4*)(T2 + (size_t)i1 * HDIM) + l8;
    uint4 u = *p1;
    uint4 v = *p2;

    float s = 0.f;
    {
        u32 ua[4] = {u.x, u.y, u.z, u.w};
        u32 va[4] = {v.x, v.y, v.z, v.w};
#pragma unroll
        for (int i = 0; i < 4; ++i) {
            float alo = __uint_as_float(ua[i] << 16);
            float ahi = __uint_as_float(ua[i] & 0xffff0000u);
            float blo = __uint_as_float(va[i] << 16);
            float bhi = __uint_as_float(va[i] & 0xffff0000u);
            s = fmaf(alo, blo, s);
            s = fmaf(ahi, bhi, s);
        }
    }
    s += __shfl_xor(s, 1, 64);
    s += __shfl_xor(s, 2, 64);
    s += __shfl_xor(s, 4, 64);
    if (l8 == 0) out[e] = s + bil_b[0];
}

// ---------- fallback: per-edge full recompute (if ws too small) ----------
__device__ __forceinline__ float lnorm_w(float v, float g, float b) {
    float mu = wave_sum64(v) * 0.015625f;
    float d  = v - mu;
    float var = wave_sum64(d * d) * 0.015625f;
    return d * rsqrtf(var + EPS) * g + b;
}

__global__ __launch_bounds__(256) void edge_direct_kernel(
    const float* __restrict__ z, const int* __restrict__ arcs,
    const float* __restrict__ root_w, const float* __restrict__ root_b,
    const float* __restrict__ lin1_w, const float* __restrict__ lin1_b,
    const float* __restrict__ lin2_w, const float* __restrict__ lin2_b,
    const float* __restrict__ bil_w, const float* __restrict__ bil_b,
    const float* __restrict__ norm_g, const float* __restrict__ norm_b,
    float* __restrict__ out, int E, int nnodes)
{
    __shared__ float W1t[4096], W2t[4096], Bs[4096];
    const int tid = threadIdx.x;
    for (int i = tid; i < 4096; i += 256) {
        int h = i >> 6, k = i & 63;
        W1t[(k << 6) | h] = lin1_w[i];
        W2t[(k << 6) | h] = lin2_w[i];
        Bs[i] = bil_w[i];
    }
    __syncthreads();

    const int lane = tid & 63;
    const float g  = norm_g[lane], bt = norm_b[lane];
    const float b1 = lin1_b[lane], b2 = lin2_b[lane];
    const float rootv = root_w[lane] + root_b[lane];

    const int gwave = (blockIdx.x * 256 + tid) >> 6;
    const int nwaves = (gridDim.x * 256) >> 6;

    for (int e = gwave; e < E; e += nwaves) {
        int i0 = arcs[2 * e], i1 = arcs[2 * e + 1];
        float v0 = (i0 == 0) ? rootv : z[(size_t)(i0 - 1) * HDIM + lane];
        float v1 = (i1 == 0) ? rootv : z[(size_t)(i1 - 1) * HDIM + lane];
        float l0 = lnorm_w(v0, g, bt);
        float l1 = lnorm_w(v1, g, bt);
        float a1 = 0.f, a2 = 0.f;
#pragma unroll
        for (int k = 0; k < 64; ++k) {
            a1 = fmaf(bcast(l0, k), W1t[(k << 6) | lane], a1);
            a2 = fmaf(bcast(l1, k), W2t[(k << 6) | lane], a2);
        }
        float x1 = lnorm_w(fmaxf(a1 + b1, 0.f), g, bt);
        float x2 = lnorm_w(fmaxf(a2 + b2, 0.f), g, bt);
        float w1 = 0.f;
#pragma unroll
        for (int h = 0; h < 64; ++h)
            w1 = fmaf(bcast(x1, h), Bs[(h << 6) | lane], w1);
        float sc = wave_sum64(w1 * x2);
        if (lane == 0) out[e] = sc + bil_b[0];
    }
}

// ---------- launch ----------
extern "C" void kernel_launch(void* const* d_in, const int* in_sizes, int n_in,
                              void* d_out, int out_size, void* d_ws, size_t ws_size,
                              hipStream_t stream) {
    const float* z      = (const float*)d_in[0];
    const int*   arcs   = (const int*)  d_in[1];
    const float* root_w = (const float*)d_in[2];
    const float* root_b = (const float*)d_in[3];
    const float* lin1_w = (const float*)d_in[4];
    const float* lin1_b = (const float*)d_in[5];
    const float* lin2_w = (const float*)d_in[6];
    const float* lin2_b = (const float*)d_in[7];
    const float* bil_w  = (const float*)d_in[8];
    const float* bil_b  = (const float*)d_in[9];
    const float* norm_g = (const float*)d_in[10];
    const float* norm_b = (const float*)d_in[11];
    float* out = (float*)d_out;

    const int E      = in_sizes[1] / 2;
    const int nnodes = in_sizes[0] / HDIM + 1;

    const size_t tbl  = (size_t)nnodes * HDIM * sizeof(u16);
    const size_t need = 2 * tbl;

    if (ws_size >= need) {
        u16* T1 = (u16*)d_ws;
        u16* T2 = (u16*)((char*)d_ws + tbl);

        const int blocks1 = (nnodes + 255) / 256;
        phase1_kernel<<<blocks1, 256, 0, stream>>>(
            z, root_w, root_b, lin1_w, lin1_b, lin2_w, lin2_b,
            bil_w, norm_g, norm_b, T1, T2, nnodes);

        const long long thr2 = (long long)E * 8;
        const int blocks2 = (int)((thr2 + 255) / 256);
        phase2_kernel<<<blocks2, 256, 0, stream>>>(arcs, T1, T2, bil_b, out, E);
    } else {
        edge_direct_kernel<<<8192, 256, 0, stream>>>(
            z, arcs, root_w, root_b, lin1_w, lin1_b, lin2_w, lin2_b,
            bil_w, bil_b, norm_g, norm_b, out, E, nnodes);
    }
}